// Round 6
// baseline (303.332 us; speedup 1.0000x reference)
//
#include <hip/hip_runtime.h>
#include <stdint.h>

#define TPB 512

constexpr int Bb   = 8;    // batch
constexpr int Vv   = 200;  // vertices
constexpr int Tt   = 128;  // time
constexpr int CIN  = 128;  // concat channels
constexpr int COUT = 64;   // K_HEADS * D_HEAD

typedef __attribute__((ext_vector_type(8))) short bf16x8;
typedef __attribute__((ext_vector_type(4))) short short4v;
typedef __attribute__((ext_vector_type(4))) float f32x4;

// bf16 helpers (manual RNE)
__device__ __forceinline__ unsigned short f2bf(float f) {
    union { float f; unsigned u; } x; x.f = f;
    unsigned r = x.u + 0x7fffu + ((x.u >> 16) & 1u);
    return (unsigned short)(r >> 16);
}
__device__ __forceinline__ unsigned pk2(float a, float b) {
    return (unsigned)f2bf(a) | ((unsigned)f2bf(b) << 16);
}

#if __has_builtin(__builtin_amdgcn_mfma_f32_16x16x16bf16_1k)
#define MFMA16(a, b, c) __builtin_amdgcn_mfma_f32_16x16x16bf16_1k(a, b, c, 0, 0, 0)
#else
__device__ __forceinline__ f32x4 mfma16_asm(short4v a, short4v b, f32x4 c) {
    f32x4 d;
    asm("v_mfma_f32_16x16x16_bf16 %0, %1, %2, %3" : "=v"(d) : "v"(a), "v"(b), "v"(c));
    return d;
}
#define MFMA16(a, b, c) mfma16_asm(a, b, c)
#endif

// ---- prep: convert W's to bf16 A-FRAGMENT order into d_ws ----
// QKV frags [0,24576): frag f=(p*4+ot_)*4+kc, 512 elts: [lane][e] =
//   W_p[ot_*16+(lane&15)][kc*32+(lane>>4)*8+e]  -> wave A-frag load = 1KB coalesced.
// Wo frags  [24576,28672): f2=ot_*2+kc, same per-frag layout vs Wo (64 cols).
__global__ void prep_w(const float* __restrict__ Wq, const float* __restrict__ Wk,
                       const float* __restrict__ Wv, const float* __restrict__ Wo,
                       unsigned short* __restrict__ ws) {
    int i = blockIdx.x * 256 + threadIdx.x;  // 0..28671
    if (i < 24576) {
        int f = i >> 9, r = i & 511;
        int l = r >> 3, e = r & 7;
        int p = f >> 4, ot_ = (f >> 2) & 3, kc = f & 3;
        int row = ot_ * 16 + (l & 15);
        int col = kc * 32 + (l >> 4) * 8 + e;
        const float* W = (p == 0) ? Wq : ((p == 1) ? Wk : Wv);
        ws[i] = f2bf(W[row * 128 + col]);
    } else {
        int i2 = i - 24576;
        int f = i2 >> 9, r = i2 & 511;
        int l = r >> 3, e = r & 7;
        int ot_ = f >> 1, kc = f & 1;
        int row = ot_ * 16 + (l & 15);
        int col = kc * 32 + (l >> 4) * 8 + e;
        ws[i] = f2bf(Wo[row * 64 + col]);
    }
}

// One block per (b, v). LDS (64 KB):
//   qk  bf16 Q[128][64] @0, K[128][64] @16384  (8B-chunk swizzle: phys_hc = hc ^ (t&14))
//   vt  bf16 VT[64 dg][128 s] @32768           (col swizzle: s_phys = s ^ (((dg>>2)&3)<<4))
//   xt  bf16 [64 t][128 c] @49152 (phase 1)  /  ot bf16 [128 t][64 i] @49152 (phase 2/3)
__global__ __launch_bounds__(TPB, 4)
void tatt_fused(const float* __restrict__ x, const float* __restrict__ tem,
                const float* __restrict__ bq, const float* __restrict__ bk,
                const float* __restrict__ bv, const float* __restrict__ bo,
                const unsigned short* __restrict__ ws,
                float* __restrict__ out)
{
    __shared__ __align__(16) unsigned char smem[65536];
    unsigned short* qk = (unsigned short*)smem;            // Q @0 (elts), K @8192 (elts)
    unsigned short* vt = (unsigned short*)(smem + 32768);  // VT [64][128]
    unsigned short* xt = (unsigned short*)(smem + 49152);
    unsigned short* ot = (unsigned short*)(smem + 49152);

    const int tid = threadIdx.x;
    const int w = tid >> 6, lane = tid & 63;
    const int l15 = lane & 15, qd = lane >> 4;
    const int b = blockIdx.x / Vv, v = blockIdx.x % Vv;
    const float QS = 1.44269504088896f * 0.35355339059327f;  // log2(e)/sqrt(8)

    // ---------------- phase 1: QKV projection via MFMA, two t-halves ----------------
    // staging mapping (coalesced): thread -> c = tid>>2, t-quarter = tid&3
    const int cS = tid >> 2, tqS = tid & 3;
    const float* srcBase = (cS < 64 ? x : tem) + ((long)(b * 64 + (cS & 63)) * Vv + v) * Tt;

    for (int half = 0; half < 2; ++half) {
        __syncthreads();  // xt free (prev half's B-frag reads done)
        #pragma unroll
        for (int k = 0; k < 4; ++k) {
            float4 f = *(const float4*)(srcBase + half * 64 + k * 16 + tqS * 4);
            float fv[4] = {f.x, f.y, f.z, f.w};
            #pragma unroll
            for (int j = 0; j < 4; ++j) {
                int t = k * 16 + tqS * 4 + j;  // local t 0..63
                xt[t * CIN + (((cS >> 3) ^ (t & 15)) << 3) + (cS & 7)] = f2bf(fv[j]);
            }
        }
        __syncthreads();
        // 48 tiles (p, ot_, tt) of 16x16, 6 per wave, K=128; A-frags from
        // fragment-ordered ws: each load = coalesced 16B/lane over 1KB block.
        #pragma unroll
        for (int j = 0; j < 6; ++j) {
            int tile = w * 6 + j;
            int p = tile >> 4, rem = tile & 15;
            int ot_ = rem & 3, tt = rem >> 2;
            int cmb = p * 4 + ot_;
            f32x4 acc = {0.f, 0.f, 0.f, 0.f};
            const unsigned short* Bbp = xt + (tt * 16 + l15) * CIN;
            #pragma unroll
            for (int kc = 0; kc < 4; ++kc) {
                bf16x8 a = *(const bf16x8*)(ws + (cmb * 4 + kc) * 512 + lane * 8);
                int phys = (kc * 4 + qd) ^ l15;
                bf16x8 bbv = *(const bf16x8*)(Bbp + phys * 8);
                acc = __builtin_amdgcn_mfma_f32_16x16x32_bf16(a, bbv, acc, 0, 0, 0);
            }
            int obase = ot_ * 16 + qd * 4;
            const float* bp_ = (p == 0) ? bq : ((p == 1) ? bk : bv);
            float4 bias = *(const float4*)(bp_ + obase);
            float bb4[4] = {bias.x, bias.y, bias.z, bias.w};
            int tg = half * 64 + tt * 16 + l15;
            if (p == 2) {
                // V stored transposed: VT[dg][t], column-swizzled by dg quad-group
                #pragma unroll
                for (int r = 0; r < 4; ++r) {
                    int dg = obase + r;
                    int tp = tg ^ ((((dg >> 2) & 3)) << 4);
                    vt[dg * 128 + tp] = f2bf(acc[r] + bb4[r]);
                }
            } else {
                // Q pre-scaled by log2(e)/sqrt(d); 8B-chunk swizzle ^(t&14)
                float sc = (p == 0) ? QS : 1.0f;
                ushort4 st4;
                st4.x = f2bf((acc[0] + bb4[0]) * sc);
                st4.y = f2bf((acc[1] + bb4[1]) * sc);
                st4.z = f2bf((acc[2] + bb4[2]) * sc);
                st4.w = f2bf((acc[3] + bb4[3]) * sc);
                int phys = (obase >> 2) ^ (tg & 14);
                *(ushort4*)(qk + p * 8192 + tg * 64 + phys * 4) = st4;
            }
        }
    }
    __syncthreads();  // Q/K/VT complete; xt dead -> ot region safe

    // ---------------- phase 2: causal attention via MFMA, wave = head ----------------
    // S^T = K·Q^T. C-layout: col=l15=t, row=qd*4+reg=s. P^T feeds PV in-place:
    // O^T = V^T·P~^T via 16x16x16 (B-layout == C-layout of S^T).
    {
        const int h = w;
        // V A-frags: lane m=l15=d (valid <8), k=qd*4+j
        short4v vfrag[8];
        {
            int dg = h * 8 + l15;
            int swz = ((dg >> 2) & 3) << 4;
            #pragma unroll
            for (int st = 0; st < 8; ++st) {
                short4v f = {0, 0, 0, 0};
                if (l15 < 8) {
                    int sp = (st * 16 + qd * 4) ^ swz;
                    f = *(const short4v*)(vt + dg * 128 + sp);
                }
                vfrag[st] = f;
            }
        }
        const int qkoff = ((h * 2) ^ (l15 & 14)) << 2;
        // hoist the 8 K-fragments (pure LDS reads, post-barrier)
        bf16x8 kfr[8];
        #pragma unroll
        for (int st = 0; st < 8; ++st) {
            bf16x8 kf = {0, 0, 0, 0, 0, 0, 0, 0};
            if (qd == 0) kf = *(const bf16x8*)(qk + 8192 + (st * 16 + l15) * 64 + qkoff);
            kfr[st] = kf;
        }
        bool dmask[4];
        #pragma unroll
        for (int r = 0; r < 4; ++r) dmask[r] = (qd * 4 + r) <= l15;  // diag: s<=t

        for (int tt = 0; tt < 8; ++tt) {
            bf16x8 qf = {0, 0, 0, 0, 0, 0, 0, 0};
            if (qd == 0) qf = *(const bf16x8*)(qk + (tt * 16 + l15) * 64 + qkoff);
            f32x4 o0 = {0.f, 0.f, 0.f, 0.f}, o1 = {0.f, 0.f, 0.f, 0.f};
            float lac = 0.f;
            #pragma unroll
            for (int st = 0; st < 8; ++st) {
                if (st <= tt) {  // causal tile skip (wave-uniform)
                    f32x4 z = {0.f, 0.f, 0.f, 0.f};
                    f32x4 s = __builtin_amdgcn_mfma_f32_16x16x32_bf16(kfr[st], qf, z, 0, 0, 0);
                    float p0 = __builtin_amdgcn_exp2f(s[0]);
                    float p1 = __builtin_amdgcn_exp2f(s[1]);
                    float p2 = __builtin_amdgcn_exp2f(s[2]);
                    float p3 = __builtin_amdgcn_exp2f(s[3]);
                    if (st == tt) {  // diagonal tile: per-element causal mask
                        p0 = dmask[0] ? p0 : 0.f;
                        p1 = dmask[1] ? p1 : 0.f;
                        p2 = dmask[2] ? p2 : 0.f;
                        p3 = dmask[3] ? p3 : 0.f;
                    }
                    lac += (p0 + p1) + (p2 + p3);
                    int pp0 = (int)pk2(p0, p1), pp1 = (int)pk2(p2, p3);
                    short4v pf;
                    pf[0] = (short)(pp0 & 0xffff); pf[1] = (short)(pp0 >> 16);
                    pf[2] = (short)(pp1 & 0xffff); pf[3] = (short)(pp1 >> 16);
                    if (st & 1) o1 = MFMA16(vfrag[st], pf, o1);
                    else        o0 = MFMA16(vfrag[st], pf, o0);
                }
            }
            float l = lac;
            l += __shfl_xor(l, 16, 64);
            l += __shfl_xor(l, 32, 64);
            float rl = __builtin_amdgcn_rcpf(l);
            if (qd < 2) {  // O^T rows d=qd*4+reg, only d<8 real
                float r0 = (o0[0] + o1[0]) * rl, r1 = (o0[1] + o1[1]) * rl;
                float r2 = (o0[2] + o1[2]) * rl, r3 = (o0[3] + o1[3]) * rl;
                int t = tt * 16 + l15;
                uint2 st2;
                st2.x = pk2(r0, r1);
                st2.y = pk2(r2, r3);
                *(uint2*)(ot + t * 64 + (((h * 2 + qd) ^ (l15 & 14)) << 2)) = st2;
            }
        }
    }
    __syncthreads();

    // ---------------- phase 3: out-projection via MFMA + bias + relu ----------------
    {
        const int tt = w;  // wave w owns t-tile w
        #pragma unroll
        for (int ot_ = 0; ot_ < 4; ++ot_) {
            f32x4 acc = {0.f, 0.f, 0.f, 0.f};
            #pragma unroll
            for (int kc = 0; kc < 2; ++kc) {
                bf16x8 a = *(const bf16x8*)(ws + 24576 + (ot_ * 2 + kc) * 512 + lane * 8);
                bf16x8 bbv = *(const bf16x8*)(ot + (tt * 16 + l15) * 64
                                 + (((kc * 8 + qd * 2) ^ (l15 & 14)) << 2));
                acc = __builtin_amdgcn_mfma_f32_16x16x32_bf16(a, bbv, acc, 0, 0, 0);
            }
            int obase = ot_ * 16 + qd * 4;
            float4 bias = *(const float4*)(bo + obase);
            float bb4[4] = {bias.x, bias.y, bias.z, bias.w};
            int t = tt * 16 + l15;
            #pragma unroll
            for (int r = 0; r < 4; ++r) {
                float val = acc[r] + bb4[r];
                out[((long)(b * COUT + obase + r) * Vv + v) * Tt + t] = val > 0.f ? val : 0.f;
            }
        }
    }
}

extern "C" void kernel_launch(void* const* d_in, const int* in_sizes, int n_in,
                              void* d_out, int out_size, void* d_ws, size_t ws_size,
                              hipStream_t stream) {
    (void)in_sizes; (void)n_in; (void)ws_size; (void)out_size;
    const float* x   = (const float*)d_in[0];
    const float* tem = (const float*)d_in[1];
    const float* Wq  = (const float*)d_in[2];
    const float* bq  = (const float*)d_in[3];
    const float* Wk  = (const float*)d_in[4];
    const float* bk  = (const float*)d_in[5];
    const float* Wv  = (const float*)d_in[6];
    const float* bv  = (const float*)d_in[7];
    const float* Wo  = (const float*)d_in[8];
    const float* bo  = (const float*)d_in[9];
    float* out = (float*)d_out;
    unsigned short* ws = (unsigned short*)d_ws;

    prep_w<<<dim3(112), dim3(256), 0, stream>>>(Wq, Wk, Wv, Wo, ws);
    tatt_fused<<<dim3(Bb * Vv), dim3(TPB), 0, stream>>>(
        x, tem, bq, bk, bv, bo, ws, out);
}